// Round 13
// baseline (1242.661 us; speedup 1.0000x reference)
//
#include <hip/hip_runtime.h>
#include <stdint.h>

// MultiHeadedSelfAttention: B=4, C=256, S=4096, O=256, H=4, D=64
// softmax over axis -2  =>  scores^T is standard flash attn with Qfa=K, Kfa=Q.
// R12: 32-row s-tiles + 4-way in-block s-split (1024-thread blocks, 16 waves)
//      -> 32 waves/CU (was 16). LDS 64KB tiles + 2KB scratch = 2 blocks/CU.
//      Two-round LDS merge tree. Proj writes re-tiled to 4KB tiles.

#define S_LEN 4096
#define HD 64
#define LOG2E 1.44269504088896f

typedef __attribute__((ext_vector_type(8))) __bf16 bf16x8;
typedef __attribute__((ext_vector_type(8))) unsigned short u16x8;
typedef __attribute__((ext_vector_type(4))) float f32x4;
typedef __attribute__((ext_vector_type(16))) float f32x16;
typedef __attribute__((ext_vector_type(4))) unsigned int u32x4;

__device__ __forceinline__ unsigned short f2bf(float f) {
    unsigned int u = __float_as_uint(f);
    u = (u + 0x7FFFu + ((u >> 16) & 1u)) >> 16;
    return (unsigned short)u;
}

__device__ __forceinline__ unsigned int cvt_pk_bf16(float lo, float hi) {
    unsigned int r;
    asm("v_cvt_pk_bf16_f32 %0, %1, %2" : "=v"(r) : "v"(lo), "v"(hi));
    return r;
}

// swaps a[32:63] <-> b[0:31]. ONLY safe when a and b hold distinct values
// (distinct registers) — proven in the v5 P-fragment path.
#define PLSWAP(a, b) asm volatile("v_permlane32_swap_b32 %0, %1" : "+v"(a), "+v"(b))

__device__ __forceinline__ void gl16(const void* g, void* l) {
    __builtin_amdgcn_global_load_lds(
        (const __attribute__((address_space(1))) unsigned int*)g,
        (__attribute__((address_space(3))) unsigned int*)l, 16, 0, 0);
}

// ---------------- X f32 [B,C,S] -> Xt bf16 [B*S, C] (float4 reads) ----------------
__global__ __launch_bounds__(256) void cvtX(const float* __restrict__ X,
                                            unsigned short* __restrict__ Xh) {
    __shared__ float LT[64][65];
    int tid = threadIdx.x;
    int id = blockIdx.x;
    int ct = id & 3;
    int st = (id >> 2) & 63;
    int b  = id >> 8;
    int sseg = (tid & 15) * 4;
    int crow = tid >> 4;
    const float* Xp = X + ((size_t)b << 20) + st * 64 + sseg;
#pragma unroll
    for (int p = 0; p < 4; p++) {
        int c = crow + p * 16;
        float4 v = *(const float4*)(Xp + ((size_t)(ct * 64 + c) << 12));
        LT[sseg + 0][c] = v.x;
        LT[sseg + 1][c] = v.y;
        LT[sseg + 2][c] = v.z;
        LT[sseg + 3][c] = v.w;
    }
    __syncthreads();
    int s = tid >> 2, cseg = (tid & 3) * 16;
    size_t ob = ((size_t)(b * S_LEN + st * 64 + s)) * 256 + ct * 64 + cseg;
#pragma unroll
    for (int hh = 0; hh < 2; hh++) {
        u16x8 vh;
#pragma unroll
        for (int i = 0; i < 8; i++) vh[i] = f2bf(LT[s][cseg + hh * 8 + i]);
        *(u16x8*)(Xh + ob + hh * 8) = vh;
    }
}

// ---------------- W f32 -> bf16. Wb layout [z][65536] ----------------
__global__ __launch_bounds__(256) void cvtW(const float* __restrict__ Wq,
                                            const float* __restrict__ Wk,
                                            const float* __restrict__ Wv,
                                            unsigned short* __restrict__ Wb) {
    int id = blockIdx.x;
    int z = id >> 5, blk = id & 31;
    const float* src = (z == 0) ? Wq : ((z == 1) ? Wk : Wv);
    int base = blk * 2048 + threadIdx.x * 8;
    u16x8 vh;
#pragma unroll
    for (int i = 0; i < 8; i++) vh[i] = f2bf(src[base + i]);
    *(u16x8*)(Wb + (size_t)z * 65536 + base) = vh;
}

// ---------------- fused projection GEMM: all 3 z per block ----------------
// grid 512 = mBlk(128) x oBlk(4); block 256.
// Q out: 32-row tiles [bh][tile(s>>5)][chunk(d>>3)][row(s&31)][e(d&7)]
//        (u16: tile*2048 + c*256 + r*8 + e)
// K out: row-major [bh][s][64] (read once as fragments, never staged)
// V out: [bh][tile(s>>5)][chunk((s&31)>>3)][row(d)][e(s&7)]
//        (u16: tile*2048 + c*512 + d*8 + e)
__global__ __launch_bounds__(256) void proj_gemm(
    const unsigned short* __restrict__ Xh,
    const unsigned short* __restrict__ Wb,
    const float* __restrict__ bq, const float* __restrict__ bk, const float* __restrict__ bv,
    unsigned short* __restrict__ Qt, unsigned short* __restrict__ Kt,
    unsigned short* __restrict__ Vn) {
    __shared__ unsigned short TL[64][136];
    int tid = threadIdx.x, lane = tid & 63, wv = tid >> 6;
    int l16 = lane & 15, lg = lane >> 4;
    int bid = blockIdx.x;
    int mBlk = bid & 127, oBlk = bid >> 7;

    int sBase = mBlk * 128 + (wv & 1) * 64;
    int oBase = oBlk * 64 + (wv >> 1) * 32;
    int b = mBlk >> 5;

    const unsigned short* Ah_p = Xh + (size_t)(sBase + l16) * 256 + lg * 8;
    const float* biases[3] = {bq, bk, bv};

    for (int z = 0; z < 3; z++) {
        const float* bias = biases[z];
        const unsigned short* Bh_p = Wb + (size_t)z * 65536 + (size_t)(oBase + l16) * 256 + lg * 8;

        f32x4 acc[4][2] = {};
        for (int kk = 0; kk < 8; kk++) {
            int ko = kk * 32;
            bf16x8 ah[4], bh[2];
#pragma unroll
            for (int mt = 0; mt < 4; mt++)
                ah[mt] = *(const bf16x8*)(Ah_p + mt * 16 * 256 + ko);
#pragma unroll
            for (int nt = 0; nt < 2; nt++)
                bh[nt] = *(const bf16x8*)(Bh_p + nt * 16 * 256 + ko);
#pragma unroll
            for (int mt = 0; mt < 4; mt++)
#pragma unroll
                for (int nt = 0; nt < 2; nt++)
                    acc[mt][nt] = __builtin_amdgcn_mfma_f32_16x16x32_bf16(ah[mt], bh[nt], acc[mt][nt], 0, 0, 0);
        }

        float b0 = bias[oBase + l16];
        float b1 = bias[oBase + 16 + l16];
        int head = oBlk;
        size_t bhbase = (size_t)(b * 4 + head) * 262144;
        int d0 = (wv >> 1) * 32 + l16;

        if (z == 0) {
            // Q -> 32-row permuted tiles
#pragma unroll
            for (int mt = 0; mt < 4; mt++)
#pragma unroll
                for (int j = 0; j < 4; j++) {
                    int s = (mBlk & 31) * 128 + (wv & 1) * 64 + mt * 16 + lg * 4 + j;
                    size_t tb = bhbase + (size_t)(s >> 5) * 2048 + (size_t)(s & 31) * 8;
                    Qt[tb + (d0 >> 3) * 256 + (d0 & 7)]       = f2bf(acc[mt][0][j] + b0);
                    Qt[tb + ((d0 >> 3) + 2) * 256 + (d0 & 7)] = f2bf(acc[mt][1][j] + b1);
                }
        } else if (z == 1) {
            // K -> row-major [bh][s][64], pre-scaled into log2 domain
            const float sc = 0.125f * LOG2E;
            size_t rowbase = (size_t)(b * 4 + head) * S_LEN;
#pragma unroll
            for (int mt = 0; mt < 4; mt++)
#pragma unroll
                for (int j = 0; j < 4; j++) {
                    int s = (mBlk & 31) * 128 + (wv & 1) * 64 + mt * 16 + lg * 4 + j;
                    size_t off = (rowbase + s) * HD;
                    Kt[off + d0]      = f2bf((acc[mt][0][j] + b0) * sc);
                    Kt[off + d0 + 16] = f2bf((acc[mt][1][j] + b1) * sc);
                }
        } else {
            // V -> 32-row permuted tiles via LDS transpose
            int o0l = (wv >> 1) * 32 + l16;
#pragma unroll
            for (int mt = 0; mt < 4; mt++) {
                int sl = (wv & 1) * 64 + mt * 16 + lg * 4;
                *(unsigned int*)&TL[o0l][sl]          = cvt_pk_bf16(acc[mt][0][0] + b0, acc[mt][0][1] + b0);
                *(unsigned int*)&TL[o0l][sl + 2]      = cvt_pk_bf16(acc[mt][0][2] + b0, acc[mt][0][3] + b0);
                *(unsigned int*)&TL[o0l + 16][sl]     = cvt_pk_bf16(acc[mt][1][0] + b1, acc[mt][1][1] + b1);
                *(unsigned int*)&TL[o0l + 16][sl + 2] = cvt_pk_bf16(acc[mt][1][2] + b1, acc[mt][1][3] + b1);
            }
            __syncthreads();
            int ol = tid >> 2, sc0 = (tid & 3) * 32;
            int sbase = (mBlk & 31) * 128 + sc0;
#pragma unroll
            for (int u = 0; u < 4; u++) {
                int s = sbase + u * 8;
                size_t addr = bhbase + (size_t)(s >> 5) * 2048
                            + (size_t)((s & 31) >> 3) * 512 + (size_t)ol * 8;
                u16x8 v = *(u16x8*)&TL[ol][sc0 + u * 8];
                *(u16x8*)(Vn + addr) = v;
            }
        }
    }
}

// ---------------- flash attention v13: 4-way s-split, 32 waves/CU ----------------
// grid 512 = bh(16) x tblk(32) (XCD-swizzled); block 1024 = 4 s-groups x 4 t-subwaves
// LDS: Q[g][p] at g*8K + p*4K; V[g][p] at 32K + g*8K + p*4K; merge l at 64K (2KB)
__global__ __launch_bounds__(1024, 8) void attn_v13(const unsigned short* __restrict__ Qt,
                                                    const unsigned short* __restrict__ Kt,
                                                    const unsigned short* __restrict__ Vt2,
                                                    float* __restrict__ out) {
    __shared__ __align__(16) char smem[67584];
    int tid = threadIdx.x, lane = tid & 63, wv = tid >> 6;
    int l31 = lane & 31, h = lane >> 5;
    int g = wv >> 2, ws = wv & 3;

    int blk = blockIdx.x;
    int swz = (blk & 7) * 64 + (blk >> 3);   // 512 % 8 == 0: bijective
    int tblk = swz & 31, bh = swz >> 5;
    int t0 = tblk * 128 + ws * 32;

    // K fragments (B-operand): col t = t0+l31, k(d) = u*16 + h*8 + i (one-time gather)
    const unsigned short* kp = Kt + ((size_t)bh * S_LEN + t0 + l31) * HD + h * 8;
    bf16x8 kf[4];
#pragma unroll
    for (int u = 0; u < 4; u++) kf[u] = *(const bf16x8*)(kp + u * 16);

    const char* Qg = (const char*)(Qt + (size_t)bh * 262144);   // 4KB per 32-row tile
    const char* Vg = (const char*)(Vt2 + (size_t)bh * 262144);  // 4KB per 32-row tile

    // staging: group's 4 waves copy the 4KB tile linearly (1 gl16 per tensor per wave)
    int srcA = ws * 1024 + lane * 16;

    char* Qbase = smem + g * 8192;
    char* Vbase = smem + 32768 + g * 8192;

    // Q read: chunk (u*2+h) of 512B, row l31*16.  V read: chunk (kb*2+h) of 1KB,
    // row l31*16 (+512 for d-half 1).
    const int rowb = l31 * 16;
    const int rx = l31 & 7;   // merge scratch swizzle only

    f32x16 oacc0 = {}, oacc1 = {}, lacc = {};
    const f32x16 ZV = {};

    u16x8 ou;
#pragma unroll
    for (int i = 0; i < 8; i++) ou[i] = 0x3F80;
    bf16x8 ones = (bf16x8)ou;

#define STAGE13(p, t) do {                                  \
        gl16(Qg + (size_t)(t) * 4096 + srcA, Qbase + (p) * 4096 + ws * 1024); \
        gl16(Vg + (size_t)(t) * 4096 + srcA, Vbase + (p) * 4096 + ws * 1024); \
    } while (0)

    STAGE13(0, g);                 // group g's first tile
    __syncthreads();

    for (int it = 0; it < 32; ++it) {
        char* Qb = Qbase + (it & 1) * 4096;
        char* Vb = Vbase + (it & 1) * 4096;
        if (it < 31) STAGE13((it & 1) ^ 1, 4 * it + 4 + g);

        // ---- QK^T: D[s_row(32), t_col(32)] (log2-domain, K pre-scaled) ----
        __builtin_amdgcn_s_setprio(1);
        f32x16 s0;
        {
            bf16x8 q = *(const bf16x8*)(Qb + ((0 * 2 + h) << 9) + rowb);
            s0 = __builtin_amdgcn_mfma_f32_32x32x16_bf16(q, kf[0], ZV, 0, 0, 0);
        }
#pragma unroll
        for (int u = 1; u < 4; u++) {
            bf16x8 q = *(const bf16x8*)(Qb + ((u * 2 + h) << 9) + rowb);
            s0 = __builtin_amdgcn_mfma_f32_32x32x16_bf16(q, kf[u], s0, 0, 0, 0);
        }
        __builtin_amdgcn_s_setprio(0);

        // ---- P = exp2(s) raw (v_exp_f32): common scale cancels in the ratio ----
#pragma unroll
        for (int r = 0; r < 16; r++) s0[r] = __builtin_amdgcn_exp2f(s0[r]);

        // ---- P -> bf16 B-fragments in-register (cvt_pk + permlane32_swap) ----
        unsigned int W0[4][2];
#pragma unroll
        for (int q = 0; q < 4; q++)
#pragma unroll
            for (int ip = 0; ip < 2; ip++)
                W0[q][ip] = cvt_pk_bf16(s0[4 * q + 2 * ip], s0[4 * q + 2 * ip + 1]);
        u32x4 pw0, pw1;
        {
            unsigned int a0 = W0[0][0], b0 = W0[1][0]; PLSWAP(a0, b0);
            unsigned int a1 = W0[0][1], b1 = W0[1][1]; PLSWAP(a1, b1);
            pw0 = (u32x4){a0, a1, b0, b1};
            unsigned int c0s = W0[2][0], d0s = W0[3][0]; PLSWAP(c0s, d0s);
            unsigned int c1s = W0[2][1], d1s = W0[3][1]; PLSWAP(c1s, d1s);
            pw1 = (u32x4){c0s, c1s, d0s, d1s};
        }
        bf16x8 pb0 = *(bf16x8*)&pw0, pb1 = *(bf16x8*)&pw1;

        // ---- O += V . P (D[d_row, t_col]) + l-sum via ones-MFMA ----
        __builtin_amdgcn_s_setprio(1);
#pragma unroll
        for (int kb = 0; kb < 2; kb++) {
            bf16x8 pb = (kb == 0) ? pb0 : pb1;
            bf16x8 v0 = *(const bf16x8*)(Vb + ((kb * 2 + h) << 10) + rowb);
            bf16x8 v1 = *(const bf16x8*)(Vb + ((kb * 2 + h) << 10) + rowb + 512);
            oacc0 = __builtin_amdgcn_mfma_f32_32x32x16_bf16(v0, pb, oacc0, 0, 0, 0);
            oacc1 = __builtin_amdgcn_mfma_f32_32x32x16_bf16(v1, pb, oacc1, 0, 0, 0);
            lacc  = __builtin_amdgcn_mfma_f32_32x32x16_bf16(ones, pb, lacc, 0, 0, 0);
        }
        __builtin_amdgcn_s_setprio(0);

        __syncthreads();  // staged tile ready + all reads of Qb/Vb done
    }

    // ---- merge the 4 s-groups via LDS tree: g1->g0, g3->g2, then g2->g0 ----
    float l = lacc[0];

    // round 1: odd groups publish
    if (g & 1) {
        int reg = g >> 1;
        float* ob = (float*)(smem + reg * 32768 + ws * 8192) + lane * 32;
#pragma unroll
        for (int r = 0; r < 16; r++) {
            ob[(((r >> 2) ^ rx) << 2) + (r & 3)]       = oacc0[r];
            ob[((((r >> 2) + 4) ^ rx) << 2) + (r & 3)] = oacc1[r];
        }
        float* ml = (float*)(smem + 65536 + reg * 1024 + ws * 256);
        ml[lane] = l;
    }
    __syncthreads();
    if (!(g & 1)) {
        int reg = g >> 1;
        const float* ob = (const float*)(smem + reg * 32768 + ws * 8192) + lane * 32;
#pragma unroll
        for (int r = 0; r < 16; r++) {
            oacc0[r] += ob[(((r >> 2) ^ rx) << 2) + (r & 3)];
            oacc1[r] += ob[((((r >> 2) + 4) ^ rx) << 2) + (r & 3)];
        }
        const float* ml = (const float*)(smem + 65536 + reg * 1024 + ws * 256);
        l += ml[lane];
    }
    __syncthreads();
    // round 2: g2 publishes to region 0
    if (g == 2) {
        float* ob = (float*)(smem + ws * 8192) + lane * 32;
#pragma unroll
        for (int r = 0; r < 16; r++) {
            ob[(((r >> 2) ^ rx) << 2) + (r & 3)]       = oacc0[r];
            ob[((((r >> 2) + 4) ^ rx) << 2) + (r & 3)] = oacc1[r];
        }
        float* ml = (float*)(smem + 65536 + ws * 256);
        ml[lane] = l;
    }
    __syncthreads();
    if (g == 0) {
        const float* ob = (const float*)(smem + ws * 8192) + lane * 32;
        const float* ml = (const float*)(smem + 65536 + ws * 256);
        float rinv = 1.0f / (l + ml[lane]);

        float* op = out + (size_t)(bh * 64) * S_LEN + t0 + l31;
#pragma unroll
        for (int r = 0; r < 16; r++) {
            int d = (r & 3) + 8 * (r >> 2) + 4 * h;
            float vB0 = ob[(((r >> 2) ^ rx) << 2) + (r & 3)];
            float vB1 = ob[((((r >> 2) + 4) ^ rx) << 2) + (r & 3)];
            op[(size_t)d * S_LEN]        = (oacc0[r] + vB0) * rinv;
            op[(size_t)(d + 32) * S_LEN] = (oacc1[r] + vB1) * rinv;
        }
    }
}

extern "C" void kernel_launch(void* const* d_in, const int* in_sizes, int n_in,
                              void* d_out, int out_size, void* d_ws, size_t ws_size,
                              hipStream_t stream) {
    const float* X  = (const float*)d_in[0];
    const float* Wq = (const float*)d_in[1];
    const float* bq = (const float*)d_in[2];
    const float* Wk = (const float*)d_in[3];
    const float* bk = (const float*)d_in[4];
    const float* Wv = (const float*)d_in[5];
    const float* bv = (const float*)d_in[6];
    float* out = (float*)d_out;

    const size_t ELEMS = (size_t)16 * S_LEN * HD;
    unsigned short* Qt = (unsigned short*)d_ws;
    unsigned short* Kt = Qt + ELEMS;
    unsigned short* Vn = Kt + ELEMS;
    unsigned short* Wb = Vn + ELEMS;   // 3*65536 u16

    unsigned short* Xh = (unsigned short*)d_out;   // consumed before attn writes out

    cvtX<<<1024, 256, 0, stream>>>(X, Xh);
    cvtW<<<96, 256, 0, stream>>>(Wq, Wk, Wv, Wb);
    proj_gemm<<<512, 256, 0, stream>>>(Xh, Wb, bq, bk, bv, Qt, Kt, Vn);
    attn_v13<<<512, 1024, 0, stream>>>(Qt, Kt, Vn, out);
}

// Round 14
// 121.251 us; speedup vs baseline: 10.2487x; 10.2487x over previous
//
#include <hip/hip_runtime.h>
#include <stdint.h>

// MultiHeadedSelfAttention: B=4, C=256, S=4096, O=256, H=4, D=64
// softmax over axis -2  =>  scores^T is standard flash attn with Qfa=K, Kfa=Q.
// R13: revert attn to v12 (v13's launch_bounds(1024,8) forced 64-reg budget ->
//      accumulator spill -> 6GB scratch traffic). proj split into z01/z2 blocks
//      (grid 1024, 2x blocks/CU); cvtW folded into cvtX launch.

#define S_LEN 4096
#define HD 64
#define LOG2E 1.44269504088896f

typedef __attribute__((ext_vector_type(8))) __bf16 bf16x8;
typedef __attribute__((ext_vector_type(8))) unsigned short u16x8;
typedef __attribute__((ext_vector_type(4))) float f32x4;
typedef __attribute__((ext_vector_type(16))) float f32x16;
typedef __attribute__((ext_vector_type(4))) unsigned int u32x4;

__device__ __forceinline__ unsigned short f2bf(float f) {
    unsigned int u = __float_as_uint(f);
    u = (u + 0x7FFFu + ((u >> 16) & 1u)) >> 16;
    return (unsigned short)u;
}

__device__ __forceinline__ unsigned int cvt_pk_bf16(float lo, float hi) {
    unsigned int r;
    asm("v_cvt_pk_bf16_f32 %0, %1, %2" : "=v"(r) : "v"(lo), "v"(hi));
    return r;
}

// swaps a[32:63] <-> b[0:31]. ONLY safe when a and b hold distinct values
// (distinct registers) — proven in the v5 P-fragment path.
#define PLSWAP(a, b) asm volatile("v_permlane32_swap_b32 %0, %1" : "+v"(a), "+v"(b))

__device__ __forceinline__ void gl16(const void* g, void* l) {
    __builtin_amdgcn_global_load_lds(
        (const __attribute__((address_space(1))) unsigned int*)g,
        (__attribute__((address_space(3))) unsigned int*)l, 16, 0, 0);
}

// ---------------- X f32 [B,C,S] -> Xt bf16 [B*S, C]; W f32 -> bf16 (fused) ----------------
// grid 1120: blocks 0-1023 = cvtX tiles; blocks 1024-1119 = cvtW (z*32 + blk)
__global__ __launch_bounds__(256) void cvtXW(const float* __restrict__ X,
                                             unsigned short* __restrict__ Xh,
                                             const float* __restrict__ Wq,
                                             const float* __restrict__ Wk,
                                             const float* __restrict__ Wv,
                                             unsigned short* __restrict__ Wb) {
    __shared__ float LT[64][65];
    int tid = threadIdx.x;
    int id = blockIdx.x;
    if (id >= 1024) {
        int wid = id - 1024;
        int z = wid >> 5, blk = wid & 31;
        const float* src = (z == 0) ? Wq : ((z == 1) ? Wk : Wv);
        int base = blk * 2048 + tid * 8;
        u16x8 vh;
#pragma unroll
        for (int i = 0; i < 8; i++) vh[i] = f2bf(src[base + i]);
        *(u16x8*)(Wb + (size_t)z * 65536 + base) = vh;
        return;
    }
    int ct = id & 3;
    int st = (id >> 2) & 63;
    int b  = id >> 8;
    int sseg = (tid & 15) * 4;
    int crow = tid >> 4;
    const float* Xp = X + ((size_t)b << 20) + st * 64 + sseg;
#pragma unroll
    for (int p = 0; p < 4; p++) {
        int c = crow + p * 16;
        float4 v = *(const float4*)(Xp + ((size_t)(ct * 64 + c) << 12));
        LT[sseg + 0][c] = v.x;
        LT[sseg + 1][c] = v.y;
        LT[sseg + 2][c] = v.z;
        LT[sseg + 3][c] = v.w;
    }
    __syncthreads();
    int s = tid >> 2, cseg = (tid & 3) * 16;
    size_t ob = ((size_t)(b * S_LEN + st * 64 + s)) * 256 + ct * 64 + cseg;
#pragma unroll
    for (int hh = 0; hh < 2; hh++) {
        u16x8 vh;
#pragma unroll
        for (int i = 0; i < 8; i++) vh[i] = f2bf(LT[s][cseg + hh * 8 + i]);
        *(u16x8*)(Xh + ob + hh * 8) = vh;
    }
}

// ---------------- projection GEMM, split into z01 (Q,K) and z2 (V) blocks ----------------
// grid 1024: bid<512 -> z in {0,1}; bid>=512 -> z=2. r = bid&511: mBlk=r&127, oBlk=r>>7.
// Q out: [bh][tile(s>>6)][chunk(d>>3)][row(s&63)][e(d&7)]  (u16: tile*4096 + c*512 + r*8 + e)
// K out: row-major [bh][s][64], pre-scaled (1/8)*log2e
// V out: [bh][tile(s>>6)][chunk((s&63)>>3)][row(d)][e(s&7)]
__global__ __launch_bounds__(256) void proj_gemm(
    const unsigned short* __restrict__ Xh,
    const unsigned short* __restrict__ Wb,
    const float* __restrict__ bq, const float* __restrict__ bk, const float* __restrict__ bv,
    unsigned short* __restrict__ Qt, unsigned short* __restrict__ Kt,
    unsigned short* __restrict__ Vn) {
    __shared__ unsigned short TL[64][136];
    int tid = threadIdx.x, lane = tid & 63, wv = tid >> 6;
    int l16 = lane & 15, lg = lane >> 4;
    int bid = blockIdx.x;
    int r = bid & 511;
    int mBlk = r & 127, oBlk = r >> 7;
    int zlo = (bid < 512) ? 0 : 2;
    int zhi = (bid < 512) ? 2 : 3;

    int sBase = mBlk * 128 + (wv & 1) * 64;
    int oBase = oBlk * 64 + (wv >> 1) * 32;
    int b = mBlk >> 5;

    const unsigned short* Ah_p = Xh + (size_t)(sBase + l16) * 256 + lg * 8;
    const float* biases[3] = {bq, bk, bv};

    for (int z = zlo; z < zhi; z++) {
        const float* bias = biases[z];
        const unsigned short* Bh_p = Wb + (size_t)z * 65536 + (size_t)(oBase + l16) * 256 + lg * 8;

        f32x4 acc[4][2] = {};
        for (int kk = 0; kk < 8; kk++) {
            int ko = kk * 32;
            bf16x8 ah[4], bh[2];
#pragma unroll
            for (int mt = 0; mt < 4; mt++)
                ah[mt] = *(const bf16x8*)(Ah_p + mt * 16 * 256 + ko);
#pragma unroll
            for (int nt = 0; nt < 2; nt++)
                bh[nt] = *(const bf16x8*)(Bh_p + nt * 16 * 256 + ko);
#pragma unroll
            for (int mt = 0; mt < 4; mt++)
#pragma unroll
                for (int nt = 0; nt < 2; nt++)
                    acc[mt][nt] = __builtin_amdgcn_mfma_f32_16x16x32_bf16(ah[mt], bh[nt], acc[mt][nt], 0, 0, 0);
        }

        float b0 = bias[oBase + l16];
        float b1 = bias[oBase + 16 + l16];
        int head = oBlk;
        size_t bhbase = (size_t)(b * 4 + head) * 262144;
        int d0 = (wv >> 1) * 32 + l16;

        if (z == 0) {
            // Q -> permuted tile layout
#pragma unroll
            for (int mt = 0; mt < 4; mt++)
#pragma unroll
                for (int j = 0; j < 4; j++) {
                    int s = (mBlk & 31) * 128 + (wv & 1) * 64 + mt * 16 + lg * 4 + j;
                    size_t tb = bhbase + (size_t)(s >> 6) * 4096 + (size_t)(s & 63) * 8;
                    Qt[tb + (d0 >> 3) * 512 + (d0 & 7)]       = f2bf(acc[mt][0][j] + b0);
                    Qt[tb + ((d0 >> 3) + 2) * 512 + (d0 & 7)] = f2bf(acc[mt][1][j] + b1);
                }
        } else if (z == 1) {
            // K -> row-major [bh][s][64], pre-scaled into log2 domain
            const float sc = 0.125f * LOG2E;
            size_t rowbase = (size_t)(b * 4 + head) * S_LEN;
#pragma unroll
            for (int mt = 0; mt < 4; mt++)
#pragma unroll
                for (int j = 0; j < 4; j++) {
                    int s = (mBlk & 31) * 128 + (wv & 1) * 64 + mt * 16 + lg * 4 + j;
                    size_t off = (rowbase + s) * HD;
                    Kt[off + d0]      = f2bf((acc[mt][0][j] + b0) * sc);
                    Kt[off + d0 + 16] = f2bf((acc[mt][1][j] + b1) * sc);
                }
        } else {
            // V -> permuted tile layout via LDS transpose
            int o0l = (wv >> 1) * 32 + l16;
#pragma unroll
            for (int mt = 0; mt < 4; mt++) {
                int sl = (wv & 1) * 64 + mt * 16 + lg * 4;
                *(unsigned int*)&TL[o0l][sl]          = cvt_pk_bf16(acc[mt][0][0] + b0, acc[mt][0][1] + b0);
                *(unsigned int*)&TL[o0l][sl + 2]      = cvt_pk_bf16(acc[mt][0][2] + b0, acc[mt][0][3] + b0);
                *(unsigned int*)&TL[o0l + 16][sl]     = cvt_pk_bf16(acc[mt][1][0] + b1, acc[mt][1][1] + b1);
                *(unsigned int*)&TL[o0l + 16][sl + 2] = cvt_pk_bf16(acc[mt][1][2] + b1, acc[mt][1][3] + b1);
            }
            __syncthreads();
            int ol = tid >> 2, sc0 = (tid & 3) * 32;
            int sbase = (mBlk & 31) * 128 + sc0;
#pragma unroll
            for (int u = 0; u < 4; u++) {
                int s = sbase + u * 8;
                size_t addr = bhbase + (size_t)(s >> 6) * 4096
                            + (size_t)((s & 63) >> 3) * 512 + (size_t)ol * 8;
                u16x8 v = *(u16x8*)&TL[ol][sc0 + u * 8];
                *(u16x8*)(Vn + addr) = v;
            }
        }
    }
}

// ---------------- flash attention v14 (= proven v12): linear staging + conflict-free b128 ----
// grid 512 = bh(16) x tblk(32) (XCD-swizzled); block 512 = 2 s-groups x 4 t-subwaves
// LDS 64KB: Q[g][p] at g*16K + p*8K; V[g][p] at 32K + g*16K + p*8K
__global__ __launch_bounds__(512, 4) void attn_v14(const unsigned short* __restrict__ Qt,
                                                   const unsigned short* __restrict__ Kt,
                                                   const unsigned short* __restrict__ Vt2,
                                                   float* __restrict__ out) {
    __shared__ __align__(16) char smem[65536];
    int tid = threadIdx.x, lane = tid & 63, wv = tid >> 6;
    int l31 = lane & 31, h = lane >> 5;
    int g = wv >> 2, ws = wv & 3;

    int blk = blockIdx.x;
    int swz = (blk & 7) * 64 + (blk >> 3);   // 512 % 8 == 0: bijective
    int tblk = swz & 31, bh = swz >> 5;
    int t0 = tblk * 128 + ws * 32;

    const unsigned short* kp = Kt + ((size_t)bh * S_LEN + t0 + l31) * HD + h * 8;
    bf16x8 kf[4];
#pragma unroll
    for (int u = 0; u < 4; u++) kf[u] = *(const bf16x8*)(kp + u * 16);

    const char* Qg = (const char*)(Qt + (size_t)bh * 262144);   // 8KB per s-tile, permuted
    const char* Vg = (const char*)(Vt2 + (size_t)bh * 262144);  // 8KB per s-tile, permuted

    int srcA = ws * 2048 + lane * 16;
    int srcB = srcA + 1024;

    char* Qbase = smem + g * 16384;
    char* Vbase = smem + 32768 + g * 16384;

    int ch[4];
#pragma unroll
    for (int u = 0; u < 4; u++) ch[u] = ((u * 2 + h) << 10);
    const int rowb = l31 * 16;
    const int rx = l31 & 7;   // epilogue scratch swizzle only

    f32x16 oacc0 = {}, oacc1 = {}, lacc = {};
    const f32x16 ZV = {};

    u16x8 ou;
#pragma unroll
    for (int i = 0; i < 8; i++) ou[i] = 0x3F80;
    bf16x8 ones = (bf16x8)ou;

#define STAGE14(p, t) do {                                  \
        const char* qg_ = Qg + (size_t)(t) * 8192;          \
        const char* vg_ = Vg + (size_t)(t) * 8192;          \
        gl16(qg_ + srcA, Qbase + (p) * 8192 + ws * 2048);         \
        gl16(qg_ + srcB, Qbase + (p) * 8192 + ws * 2048 + 1024);  \
        gl16(vg_ + srcA, Vbase + (p) * 8192 + ws * 2048);         \
        gl16(vg_ + srcB, Vbase + (p) * 8192 + ws * 2048 + 1024);  \
    } while (0)

    STAGE14(0, g);
    __syncthreads();

    for (int it = 0; it < 32; ++it) {
        char* Qb = Qbase + (it & 1) * 8192;
        char* Vb = Vbase + (it & 1) * 8192;
        if (it < 31) STAGE14((it & 1) ^ 1, 2 * it + 2 + g);

        // ---- QK^T: D[s_row, t_col], two 32-row halves (log2-domain, K pre-scaled) ----
        __builtin_amdgcn_s_setprio(1);
        f32x16 s0, s1;
        {
            bf16x8 q = *(const bf16x8*)(Qb + ch[0] + rowb);
            s0 = __builtin_amdgcn_mfma_f32_32x32x16_bf16(q, kf[0], ZV, 0, 0, 0);
        }
#pragma unroll
        for (int u = 1; u < 4; u++) {
            bf16x8 q = *(const bf16x8*)(Qb + ch[u] + rowb);
            s0 = __builtin_amdgcn_mfma_f32_32x32x16_bf16(q, kf[u], s0, 0, 0, 0);
        }
        {
            bf16x8 q = *(const bf16x8*)(Qb + ch[0] + rowb + 512);
            s1 = __builtin_amdgcn_mfma_f32_32x32x16_bf16(q, kf[0], ZV, 0, 0, 0);
        }
#pragma unroll
        for (int u = 1; u < 4; u++) {
            bf16x8 q = *(const bf16x8*)(Qb + ch[u] + rowb + 512);
            s1 = __builtin_amdgcn_mfma_f32_32x32x16_bf16(q, kf[u], s1, 0, 0, 0);
        }
        __builtin_amdgcn_s_setprio(0);

        // ---- P = exp2(s) raw (v_exp_f32): common scale cancels in the ratio ----
#pragma unroll
        for (int r = 0; r < 16; r++) {
            s0[r] = __builtin_amdgcn_exp2f(s0[r]);
            s1[r] = __builtin_amdgcn_exp2f(s1[r]);
        }

        // ---- P -> bf16 B-fragments in-register (cvt_pk + permlane32_swap) ----
        unsigned int W0[4][2], W1[4][2];
#pragma unroll
        for (int q = 0; q < 4; q++)
#pragma unroll
            for (int ip = 0; ip < 2; ip++) {
                W0[q][ip] = cvt_pk_bf16(s0[4 * q + 2 * ip], s0[4 * q + 2 * ip + 1]);
                W1[q][ip] = cvt_pk_bf16(s1[4 * q + 2 * ip], s1[4 * q + 2 * ip + 1]);
            }
        u32x4 pw0, pw1, pw2, pw3;
        {
            unsigned int a0 = W0[0][0], b0 = W0[1][0]; PLSWAP(a0, b0);
            unsigned int a1 = W0[0][1], b1 = W0[1][1]; PLSWAP(a1, b1);
            pw0 = (u32x4){a0, a1, b0, b1};
            unsigned int c0s = W0[2][0], d0s = W0[3][0]; PLSWAP(c0s, d0s);
            unsigned int c1s = W0[2][1], d1s = W0[3][1]; PLSWAP(c1s, d1s);
            pw1 = (u32x4){c0s, c1s, d0s, d1s};
            unsigned int e0 = W1[0][0], f0 = W1[1][0]; PLSWAP(e0, f0);
            unsigned int e1 = W1[0][1], f1 = W1[1][1]; PLSWAP(e1, f1);
            pw2 = (u32x4){e0, e1, f0, f1};
            unsigned int g0 = W1[2][0], h0 = W1[3][0]; PLSWAP(g0, h0);
            unsigned int g1 = W1[2][1], h1 = W1[3][1]; PLSWAP(g1, h1);
            pw3 = (u32x4){g0, g1, h0, h1};
        }
        bf16x8 pb0 = *(bf16x8*)&pw0, pb1 = *(bf16x8*)&pw1;
        bf16x8 pb2 = *(bf16x8*)&pw2, pb3 = *(bf16x8*)&pw3;

        // ---- O += V . P (D[d_row, t_col]) + l-sum via ones-MFMA ----
        __builtin_amdgcn_s_setprio(1);
#pragma unroll
        for (int b2 = 0; b2 < 4; b2++) {
            bf16x8 pb = (b2 == 0) ? pb0 : (b2 == 1) ? pb1 : (b2 == 2) ? pb2 : pb3;
            bf16x8 v0 = *(const bf16x8*)(Vb + ch[b2] + rowb);
            bf16x8 v1 = *(const bf16x8*)(Vb + ch[b2] + rowb + 512);
            oacc0 = __builtin_amdgcn_mfma_f32_32x32x16_bf16(v0, pb, oacc0, 0, 0, 0);
            oacc1 = __builtin_amdgcn_mfma_f32_32x32x16_bf16(v1, pb, oacc1, 0, 0, 0);
            lacc  = __builtin_amdgcn_mfma_f32_32x32x16_bf16(ones, pb, lacc, 0, 0, 0);
        }
        __builtin_amdgcn_s_setprio(0);

        __syncthreads();
    }

    // ---- merge the two s-groups via LDS (plain sums — no max state) ----
    float l = lacc[0];
    if (g == 1) {
        float* ml = (float*)(smem + ws * 256);
        ml[lane] = l;
        float* ob = (float*)(smem + 32768 + ws * 8192) + lane * 32;
#pragma unroll
        for (int r = 0; r < 16; r++) {
            ob[(((r >> 2) ^ rx) << 2) + (r & 3)]       = oacc0[r];
            ob[((((r >> 2) + 4) ^ rx) << 2) + (r & 3)] = oacc1[r];
        }
    }
    __syncthreads();
    if (g == 0) {
        const float* ml = (const float*)(smem + ws * 256);
        float lB = ml[lane];
        const float* ob = (const float*)(smem + 32768 + ws * 8192) + lane * 32;
        float rinv = 1.0f / (l + lB);

        float* op = out + (size_t)(bh * 64) * S_LEN + t0 + l31;
#pragma unroll
        for (int r = 0; r < 16; r++) {
            int d = (r & 3) + 8 * (r >> 2) + 4 * h;
            float vB0 = ob[(((r >> 2) ^ rx) << 2) + (r & 3)];
            float vB1 = ob[((((r >> 2) + 4) ^ rx) << 2) + (r & 3)];
            op[(size_t)d * S_LEN]        = (oacc0[r] + vB0) * rinv;
            op[(size_t)(d + 32) * S_LEN] = (oacc1[r] + vB1) * rinv;
        }
    }
}

extern "C" void kernel_launch(void* const* d_in, const int* in_sizes, int n_in,
                              void* d_out, int out_size, void* d_ws, size_t ws_size,
                              hipStream_t stream) {
    const float* X  = (const float*)d_in[0];
    const float* Wq = (const float*)d_in[1];
    const float* bq = (const float*)d_in[2];
    const float* Wk = (const float*)d_in[3];
    const float* bk = (const float*)d_in[4];
    const float* Wv = (const float*)d_in[5];
    const float* bv = (const float*)d_in[6];
    float* out = (float*)d_out;

    const size_t ELEMS = (size_t)16 * S_LEN * HD;
    unsigned short* Qt = (unsigned short*)d_ws;
    unsigned short* Kt = Qt + ELEMS;
    unsigned short* Vn = Kt + ELEMS;
    unsigned short* Wb = Vn + ELEMS;   // 3*65536 u16

    unsigned short* Xh = (unsigned short*)d_out;   // consumed before attn writes out

    cvtXW<<<1120, 256, 0, stream>>>(X, Xh, Wq, Wk, Wv, Wb);
    proj_gemm<<<1024, 256, 0, stream>>>(Xh, Wb, bq, bk, bv, Qt, Kt, Vn);
    attn_v14<<<512, 512, 0, stream>>>(Qt, Kt, Vn, out);
}

// Round 15
// 119.078 us; speedup vs baseline: 10.4357x; 1.0183x over previous
//
#include <hip/hip_runtime.h>
#include <stdint.h>

// MultiHeadedSelfAttention: B=4, C=256, S=4096, O=256, H=4, D=64
// softmax over axis -2  =>  scores^T is standard flash attn with Qfa=K, Kfa=Q.
// R14: revert to the exact R11 configuration (best measured total, 119.6us):
//      cvtX + cvtW separate launches, proj_gemm with fused z-loop (grid 512),
//      attn = v12 (linear staging of pre-permuted tiles, conflict-free b128,
//      no-max softmax, raw v_exp_f32, ones-MFMA l-sum, 2-way s-split).

#define S_LEN 4096
#define HD 64
#define LOG2E 1.44269504088896f

typedef __attribute__((ext_vector_type(8))) __bf16 bf16x8;
typedef __attribute__((ext_vector_type(8))) unsigned short u16x8;
typedef __attribute__((ext_vector_type(4))) float f32x4;
typedef __attribute__((ext_vector_type(16))) float f32x16;
typedef __attribute__((ext_vector_type(4))) unsigned int u32x4;

__device__ __forceinline__ unsigned short f2bf(float f) {
    unsigned int u = __float_as_uint(f);
    u = (u + 0x7FFFu + ((u >> 16) & 1u)) >> 16;
    return (unsigned short)u;
}

__device__ __forceinline__ unsigned int cvt_pk_bf16(float lo, float hi) {
    unsigned int r;
    asm("v_cvt_pk_bf16_f32 %0, %1, %2" : "=v"(r) : "v"(lo), "v"(hi));
    return r;
}

// swaps a[32:63] <-> b[0:31]. ONLY safe when a and b hold distinct values
// (distinct registers) — proven in the v5 P-fragment path.
#define PLSWAP(a, b) asm volatile("v_permlane32_swap_b32 %0, %1" : "+v"(a), "+v"(b))

__device__ __forceinline__ void gl16(const void* g, void* l) {
    __builtin_amdgcn_global_load_lds(
        (const __attribute__((address_space(1))) unsigned int*)g,
        (__attribute__((address_space(3))) unsigned int*)l, 16, 0, 0);
}

// ---------------- X f32 [B,C,S] -> Xt bf16 [B*S, C] (float4 reads) ----------------
__global__ __launch_bounds__(256) void cvtX(const float* __restrict__ X,
                                            unsigned short* __restrict__ Xh) {
    __shared__ float LT[64][65];
    int tid = threadIdx.x;
    int id = blockIdx.x;
    int ct = id & 3;
    int st = (id >> 2) & 63;
    int b  = id >> 8;
    int sseg = (tid & 15) * 4;
    int crow = tid >> 4;
    const float* Xp = X + ((size_t)b << 20) + st * 64 + sseg;
#pragma unroll
    for (int p = 0; p < 4; p++) {
        int c = crow + p * 16;
        float4 v = *(const float4*)(Xp + ((size_t)(ct * 64 + c) << 12));
        LT[sseg + 0][c] = v.x;
        LT[sseg + 1][c] = v.y;
        LT[sseg + 2][c] = v.z;
        LT[sseg + 3][c] = v.w;
    }
    __syncthreads();
    int s = tid >> 2, cseg = (tid & 3) * 16;
    size_t ob = ((size_t)(b * S_LEN + st * 64 + s)) * 256 + ct * 64 + cseg;
#pragma unroll
    for (int hh = 0; hh < 2; hh++) {
        u16x8 vh;
#pragma unroll
        for (int i = 0; i < 8; i++) vh[i] = f2bf(LT[s][cseg + hh * 8 + i]);
        *(u16x8*)(Xh + ob + hh * 8) = vh;
    }
}

// ---------------- W f32 -> bf16. Wb layout [z][65536] ----------------
__global__ __launch_bounds__(256) void cvtW(const float* __restrict__ Wq,
                                            const float* __restrict__ Wk,
                                            const float* __restrict__ Wv,
                                            unsigned short* __restrict__ Wb) {
    int id = blockIdx.x;
    int z = id >> 5, blk = id & 31;
    const float* src = (z == 0) ? Wq : ((z == 1) ? Wk : Wv);
    int base = blk * 2048 + threadIdx.x * 8;
    u16x8 vh;
#pragma unroll
    for (int i = 0; i < 8; i++) vh[i] = f2bf(src[base + i]);
    *(u16x8*)(Wb + (size_t)z * 65536 + base) = vh;
}

// ---------------- fused projection GEMM: all 3 z per block ----------------
// grid 512 = mBlk(128) x oBlk(4); block 256. Xh tile read 3x but L2-hot.
// Q out: [bh][tile(s>>6)][chunk(d>>3)][row(s&63)][e(d&7)]  (u16: tile*4096 + c*512 + r*8 + e)
// K out: row-major [bh][s][64], pre-scaled (1/8)*log2e
// V out: [bh][tile(s>>6)][chunk((s&63)>>3)][row(d)][e(s&7)]
__global__ __launch_bounds__(256) void proj_gemm(
    const unsigned short* __restrict__ Xh,
    const unsigned short* __restrict__ Wb,
    const float* __restrict__ bq, const float* __restrict__ bk, const float* __restrict__ bv,
    unsigned short* __restrict__ Qt, unsigned short* __restrict__ Kt,
    unsigned short* __restrict__ Vn) {
    __shared__ unsigned short TL[64][136];
    int tid = threadIdx.x, lane = tid & 63, wv = tid >> 6;
    int l16 = lane & 15, lg = lane >> 4;
    int bid = blockIdx.x;
    int mBlk = bid & 127, oBlk = bid >> 7;

    int sBase = mBlk * 128 + (wv & 1) * 64;
    int oBase = oBlk * 64 + (wv >> 1) * 32;
    int b = mBlk >> 5;

    const unsigned short* Ah_p = Xh + (size_t)(sBase + l16) * 256 + lg * 8;
    const float* biases[3] = {bq, bk, bv};

    for (int z = 0; z < 3; z++) {
        const float* bias = biases[z];
        const unsigned short* Bh_p = Wb + (size_t)z * 65536 + (size_t)(oBase + l16) * 256 + lg * 8;

        f32x4 acc[4][2] = {};
        for (int kk = 0; kk < 8; kk++) {
            int ko = kk * 32;
            bf16x8 ah[4], bh[2];
#pragma unroll
            for (int mt = 0; mt < 4; mt++)
                ah[mt] = *(const bf16x8*)(Ah_p + mt * 16 * 256 + ko);
#pragma unroll
            for (int nt = 0; nt < 2; nt++)
                bh[nt] = *(const bf16x8*)(Bh_p + nt * 16 * 256 + ko);
#pragma unroll
            for (int mt = 0; mt < 4; mt++)
#pragma unroll
                for (int nt = 0; nt < 2; nt++)
                    acc[mt][nt] = __builtin_amdgcn_mfma_f32_16x16x32_bf16(ah[mt], bh[nt], acc[mt][nt], 0, 0, 0);
        }

        float b0 = bias[oBase + l16];
        float b1 = bias[oBase + 16 + l16];
        int head = oBlk;
        size_t bhbase = (size_t)(b * 4 + head) * 262144;
        int d0 = (wv >> 1) * 32 + l16;

        if (z == 0) {
            // Q -> permuted tile layout
#pragma unroll
            for (int mt = 0; mt < 4; mt++)
#pragma unroll
                for (int j = 0; j < 4; j++) {
                    int s = (mBlk & 31) * 128 + (wv & 1) * 64 + mt * 16 + lg * 4 + j;
                    size_t tb = bhbase + (size_t)(s >> 6) * 4096 + (size_t)(s & 63) * 8;
                    Qt[tb + (d0 >> 3) * 512 + (d0 & 7)]       = f2bf(acc[mt][0][j] + b0);
                    Qt[tb + ((d0 >> 3) + 2) * 512 + (d0 & 7)] = f2bf(acc[mt][1][j] + b1);
                }
        } else if (z == 1) {
            // K -> row-major [bh][s][64], pre-scaled into log2 domain
            const float sc = 0.125f * LOG2E;
            size_t rowbase = (size_t)(b * 4 + head) * S_LEN;
#pragma unroll
            for (int mt = 0; mt < 4; mt++)
#pragma unroll
                for (int j = 0; j < 4; j++) {
                    int s = (mBlk & 31) * 128 + (wv & 1) * 64 + mt * 16 + lg * 4 + j;
                    size_t off = (rowbase + s) * HD;
                    Kt[off + d0]      = f2bf((acc[mt][0][j] + b0) * sc);
                    Kt[off + d0 + 16] = f2bf((acc[mt][1][j] + b1) * sc);
                }
        } else {
            // V -> permuted tile layout via LDS transpose
            int o0l = (wv >> 1) * 32 + l16;
#pragma unroll
            for (int mt = 0; mt < 4; mt++) {
                int sl = (wv & 1) * 64 + mt * 16 + lg * 4;
                *(unsigned int*)&TL[o0l][sl]          = cvt_pk_bf16(acc[mt][0][0] + b0, acc[mt][0][1] + b0);
                *(unsigned int*)&TL[o0l][sl + 2]      = cvt_pk_bf16(acc[mt][0][2] + b0, acc[mt][0][3] + b0);
                *(unsigned int*)&TL[o0l + 16][sl]     = cvt_pk_bf16(acc[mt][1][0] + b1, acc[mt][1][1] + b1);
                *(unsigned int*)&TL[o0l + 16][sl + 2] = cvt_pk_bf16(acc[mt][1][2] + b1, acc[mt][1][3] + b1);
            }
            __syncthreads();
            int ol = tid >> 2, sc0 = (tid & 3) * 32;
            int sbase = (mBlk & 31) * 128 + sc0;
#pragma unroll
            for (int u = 0; u < 4; u++) {
                int s = sbase + u * 8;
                size_t addr = bhbase + (size_t)(s >> 6) * 4096
                            + (size_t)((s & 63) >> 3) * 512 + (size_t)ol * 8;
                u16x8 v = *(u16x8*)&TL[ol][sc0 + u * 8];
                *(u16x8*)(Vn + addr) = v;
            }
        }
    }
}

// ---------------- flash attention v15 (= proven v12): linear staging + conflict-free b128 ----
// grid 512 = bh(16) x tblk(32) (XCD-swizzled); block 512 = 2 s-groups x 4 t-subwaves
// LDS 64KB: Q[g][p] at g*16K + p*8K; V[g][p] at 32K + g*16K + p*8K
// Tiles arrive pre-permuted [chunk][row]; staging is an identity copy.
__global__ __launch_bounds__(512, 4) void attn_v15(const unsigned short* __restrict__ Qt,
                                                   const unsigned short* __restrict__ Kt,
                                                   const unsigned short* __restrict__ Vt2,
                                                   float* __restrict__ out) {
    __shared__ __align__(16) char smem[65536];
    int tid = threadIdx.x, lane = tid & 63, wv = tid >> 6;
    int l31 = lane & 31, h = lane >> 5;
    int g = wv >> 2, ws = wv & 3;

    int blk = blockIdx.x;
    int swz = (blk & 7) * 64 + (blk >> 3);   // 512 % 8 == 0: bijective
    int tblk = swz & 31, bh = swz >> 5;
    int t0 = tblk * 128 + ws * 32;

    const unsigned short* kp = Kt + ((size_t)bh * S_LEN + t0 + l31) * HD + h * 8;
    bf16x8 kf[4];
#pragma unroll
    for (int u = 0; u < 4; u++) kf[u] = *(const bf16x8*)(kp + u * 16);

    const char* Qg = (const char*)(Qt + (size_t)bh * 262144);   // 8KB per s-tile, permuted
    const char* Vg = (const char*)(Vt2 + (size_t)bh * 262144);  // 8KB per s-tile, permuted

    int srcA = ws * 2048 + lane * 16;
    int srcB = srcA + 1024;

    char* Qbase = smem + g * 16384;
    char* Vbase = smem + 32768 + g * 16384;

    int ch[4];
#pragma unroll
    for (int u = 0; u < 4; u++) ch[u] = ((u * 2 + h) << 10);
    const int rowb = l31 * 16;
    const int rx = l31 & 7;   // epilogue scratch swizzle only

    f32x16 oacc0 = {}, oacc1 = {}, lacc = {};
    const f32x16 ZV = {};

    u16x8 ou;
#pragma unroll
    for (int i = 0; i < 8; i++) ou[i] = 0x3F80;
    bf16x8 ones = (bf16x8)ou;

#define STAGE15(p, t) do {                                  \
        const char* qg_ = Qg + (size_t)(t) * 8192;          \
        const char* vg_ = Vg + (size_t)(t) * 8192;          \
        gl16(qg_ + srcA, Qbase + (p) * 8192 + ws * 2048);         \
        gl16(qg_ + srcB, Qbase + (p) * 8192 + ws * 2048 + 1024);  \
        gl16(vg_ + srcA, Vbase + (p) * 8192 + ws * 2048);         \
        gl16(vg_ + srcB, Vbase + (p) * 8192 + ws * 2048 + 1024);  \
    } while (0)

    STAGE15(0, g);
    __syncthreads();

    for (int it = 0; it < 32; ++it) {
        char* Qb = Qbase + (it & 1) * 8192;
        char* Vb = Vbase + (it & 1) * 8192;
        if (it < 31) STAGE15((it & 1) ^ 1, 2 * it + 2 + g);

        // ---- QK^T: D[s_row, t_col], two 32-row halves (log2-domain, K pre-scaled) ----
        __builtin_amdgcn_s_setprio(1);
        f32x16 s0, s1;
        {
            bf16x8 q = *(const bf16x8*)(Qb + ch[0] + rowb);
            s0 = __builtin_amdgcn_mfma_f32_32x32x16_bf16(q, kf[0], ZV, 0, 0, 0);
        }
#pragma unroll
        for (int u = 1; u < 4; u++) {
            bf16x8 q = *(const bf16x8*)(Qb + ch[u] + rowb);
            s0 = __builtin_amdgcn_mfma_f32_32x32x16_bf16(q, kf[u], s0, 0, 0, 0);
        }
        {
            bf16x8 q = *(const bf16x8*)(Qb + ch[0] + rowb + 512);
            s1 = __builtin_amdgcn_mfma_f32_32x32x16_bf16(q, kf[0], ZV, 0, 0, 0);
        }
#pragma unroll
        for (int u = 1; u < 4; u++) {
            bf16x8 q = *(const bf16x8*)(Qb + ch[u] + rowb + 512);
            s1 = __builtin_amdgcn_mfma_f32_32x32x16_bf16(q, kf[u], s1, 0, 0, 0);
        }
        __builtin_amdgcn_s_setprio(0);

        // ---- P = exp2(s) raw (v_exp_f32): common scale cancels in the ratio ----
#pragma unroll
        for (int r = 0; r < 16; r++) {
            s0[r] = __builtin_amdgcn_exp2f(s0[r]);
            s1[r] = __builtin_amdgcn_exp2f(s1[r]);
        }

        // ---- P -> bf16 B-fragments in-register (cvt_pk + permlane32_swap) ----
        unsigned int W0[4][2], W1[4][2];
#pragma unroll
        for (int q = 0; q < 4; q++)
#pragma unroll
            for (int ip = 0; ip < 2; ip++) {
                W0[q][ip] = cvt_pk_bf16(s0[4 * q + 2 * ip], s0[4 * q + 2 * ip + 1]);
                W1[q][ip] = cvt_pk_bf16(s1[4 * q + 2 * ip], s1[4 * q + 2 * ip + 1]);
            }
        u32x4 pw0, pw1, pw2, pw3;
        {
            unsigned int a0 = W0[0][0], b0 = W0[1][0]; PLSWAP(a0, b0);
            unsigned int a1 = W0[0][1], b1 = W0[1][1]; PLSWAP(a1, b1);
            pw0 = (u32x4){a0, a1, b0, b1};
            unsigned int c0s = W0[2][0], d0s = W0[3][0]; PLSWAP(c0s, d0s);
            unsigned int c1s = W0[2][1], d1s = W0[3][1]; PLSWAP(c1s, d1s);
            pw1 = (u32x4){c0s, c1s, d0s, d1s};
            unsigned int e0 = W1[0][0], f0 = W1[1][0]; PLSWAP(e0, f0);
            unsigned int e1 = W1[0][1], f1 = W1[1][1]; PLSWAP(e1, f1);
            pw2 = (u32x4){e0, e1, f0, f1};
            unsigned int g0 = W1[2][0], h0 = W1[3][0]; PLSWAP(g0, h0);
            unsigned int g1 = W1[2][1], h1 = W1[3][1]; PLSWAP(g1, h1);
            pw3 = (u32x4){g0, g1, h0, h1};
        }
        bf16x8 pb0 = *(bf16x8*)&pw0, pb1 = *(bf16x8*)&pw1;
        bf16x8 pb2 = *(bf16x8*)&pw2, pb3 = *(bf16x8*)&pw3;

        // ---- O += V . P (D[d_row, t_col]) + l-sum via ones-MFMA ----
        __builtin_amdgcn_s_setprio(1);
#pragma unroll
        for (int b2 = 0; b2 < 4; b2++) {
            bf16x8 pb = (b2 == 0) ? pb0 : (b2 == 1) ? pb1 : (b2 == 2) ? pb2 : pb3;
            bf16x8 v0 = *(const bf16x8*)(Vb + ch[b2] + rowb);
            bf16x8 v1 = *(const bf16x8*)(Vb + ch[b2] + rowb + 512);
            oacc0 = __builtin_amdgcn_mfma_f32_32x32x16_bf16(v0, pb, oacc0, 0, 0, 0);
            oacc1 = __builtin_amdgcn_mfma_f32_32x32x16_bf16(v1, pb, oacc1, 0, 0, 0);
            lacc  = __builtin_amdgcn_mfma_f32_32x32x16_bf16(ones, pb, lacc, 0, 0, 0);
        }
        __builtin_amdgcn_s_setprio(0);

        __syncthreads();
    }

    // ---- merge the two s-groups via LDS (plain sums — no max state) ----
    float l = lacc[0];
    if (g == 1) {
        float* ml = (float*)(smem + ws * 256);
        ml[lane] = l;
        float* ob = (float*)(smem + 32768 + ws * 8192) + lane * 32;
#pragma unroll
        for (int r = 0; r < 16; r++) {
            ob[(((r >> 2) ^ rx) << 2) + (r & 3)]       = oacc0[r];
            ob[((((r >> 2) + 4) ^ rx) << 2) + (r & 3)] = oacc1[r];
        }
    }
    __syncthreads();
    if (g == 0) {
        const float* ml = (const float*)(smem + ws * 256);
        float lB = ml[lane];
        const float* ob = (const float*)(smem + 32768 + ws * 8192) + lane * 32;
        float rinv = 1.0f / (l + lB);

        float* op = out + (size_t)(bh * 64) * S_LEN + t0 + l31;
#pragma unroll
        for (int r = 0; r < 16; r++) {
            int d = (r & 3) + 8 * (r >> 2) + 4 * h;
            float vB0 = ob[(((r >> 2) ^ rx) << 2) + (r & 3)];
            float vB1 = ob[((((r >> 2) + 4) ^ rx) << 2) + (r & 3)];
            op[(size_t)d * S_LEN]        = (oacc0[r] + vB0) * rinv;
            op[(size_t)(d + 32) * S_LEN] = (oacc1[r] + vB1) * rinv;
        }
    }
}

extern "C" void kernel_launch(void* const* d_in, const int* in_sizes, int n_in,
                              void* d_out, int out_size, void* d_ws, size_t ws_size,
                              hipStream_t stream) {
    const float* X  = (const float*)d_in[0];
    const float* Wq = (const float*)d_in[1];
    const float* bq = (const float*)d_in[2];
    const float* Wk = (const float*)d_in[3];
    const float* bk = (const float*)d_in[4];
    const float* Wv = (const float*)d_in[5];
    const float* bv = (const float*)d_in[6];
    float* out = (float*)d_out;

    const size_t ELEMS = (size_t)16 * S_LEN * HD;
    unsigned short* Qt = (unsigned short*)d_ws;
    unsigned short* Kt = Qt + ELEMS;
    unsigned short* Vn = Kt + ELEMS;
    unsigned short* Wb = Vn + ELEMS;   // 3*65536 u16

    unsigned short* Xh = (unsigned short*)d_out;   // consumed before attn writes out

    cvtX<<<1024, 256, 0, stream>>>(X, Xh);
    cvtW<<<96, 256, 0, stream>>>(Wq, Wk, Wv, Wb);
    proj_gemm<<<512, 256, 0, stream>>>(Xh, Wb, bq, bk, bv, Qt, Kt, Vn);
    attn_v15<<<512, 512, 0, stream>>>(Qt, Kt, Vn, out);
}